// Round 10
// baseline (201.336 us; speedup 1.0000x reference)
//
#include <hip/hip_runtime.h>
#include <math.h>

#define S_LEN 56
#define DH 128

typedef float f32x4 __attribute__((ext_vector_type(4)));
typedef unsigned short u16x8 __attribute__((ext_vector_type(8)));
typedef unsigned short u16x4 __attribute__((ext_vector_type(4)));

__device__ __forceinline__ unsigned short f2bf(float f) {
  unsigned int u = __builtin_bit_cast(unsigned int, f);
  u += 0x7fffu + ((u >> 16) & 1u);  // RNE
  return (unsigned short)(u >> 16);
}
__device__ __forceinline__ unsigned short tobf(float f) {
  __bf16 h = (__bf16)f;
  return __builtin_bit_cast(unsigned short, h);
}
__device__ __forceinline__ u16x4 pk4(f32x4 v) {
  u16x4 r;
  r[0] = tobf(v[0]); r[1] = tobf(v[1]); r[2] = tobf(v[2]); r[3] = tobf(v[3]);
  return r;
}
__device__ __forceinline__ u16x8 pk8(f32x4 a, f32x4 b) {
  u16x8 r;
  r[0] = tobf(a[0]); r[1] = tobf(a[1]); r[2] = tobf(a[2]); r[3] = tobf(a[3]);
  r[4] = tobf(b[0]); r[5] = tobf(b[1]); r[6] = tobf(b[2]); r[7] = tobf(b[3]);
  return r;
}
__device__ __forceinline__ u16x8 cmb(u16x4 lo, u16x4 hi) {
  u16x8 r;
  r[0] = lo[0]; r[1] = lo[1]; r[2] = lo[2]; r[3] = lo[3];
  r[4] = hi[0]; r[5] = hi[1]; r[6] = hi[2]; r[7] = hi[3];
  return r;
}
// pi-mapped fragment from a row-major bf16 matrix (r6/r7-proven operand map).
__device__ __forceinline__ u16x8 ldpi(const unsigned short* base) {
  u16x4 lo = *(const u16x4*)base;
  u16x4 hi = *(const u16x4*)(base + 16);
  return cmb(lo, hi);
}

template <typename V>
__device__ __forceinline__ auto mfma_sel(V a, V b, f32x4 c, int)
    -> decltype(__builtin_amdgcn_mfma_f32_16x16x32_bf16(a, b, c, 0, 0, 0)) {
  return __builtin_amdgcn_mfma_f32_16x16x32_bf16(a, b, c, 0, 0, 0);
}
template <typename V, typename E = __bf16>
__device__ __forceinline__ f32x4 mfma_sel(V a, V b, f32x4 c, long) {
  typedef E bfv __attribute__((ext_vector_type(8)));
  return __builtin_amdgcn_mfma_f32_16x16x32_bf16(
      __builtin_bit_cast(bfv, a), __builtin_bit_cast(bfv, b), c, 0, 0, 0);
}
__device__ __forceinline__ f32x4 MFMA(u16x8 a, u16x8 b, f32x4 c) {
  return mfma_sel(a, b, c, 0);
}

__global__ void conv_w(const float* __restrict__ wq, const float* __restrict__ wk,
                       const float* __restrict__ wv, const float* __restrict__ wo,
                       unsigned short* __restrict__ o) {
  int i = blockIdx.x * 256 + threadIdx.x;  // 0..65535
  int m = i >> 14, r = i & 16383;
  const float* src = (m == 0) ? wq : (m == 1) ? wk : (m == 2) ? wv : wo;
  o[i] = f2bf(src[r]);
}

// A^T where A = Wq^T Wk (E = x A x^T); r9-proven orientation.
__global__ void conv_a(const float* __restrict__ wq, const float* __restrict__ wk,
                       unsigned short* __restrict__ o) {
  int i = blockIdx.x * 256 + threadIdx.x;  // 0..16383
  int r = i >> 7, c = i & 127;
  float s = 0.f;
#pragma unroll 8
  for (int d = 0; d < DH; ++d) s += wq[d * DH + r] * wk[d * DH + c];
  o[4 * 16384 + c * DH + r] = f2bf(s);  // A^T[c][r] = A[r][c]
}

// TWO waves per sample (q-split: each wave owns 2 q-tiles) to halve the
// register footprint -> 3 waves/SIMD (launch_bounds(256,3)). Pipeline per
// wave (r9 math): afp (x, PERMUTED so own q-tiles sit at static indices 0,1)
// -> E = xAx^T (Y + fold, M2 trick) -> softmax -> pp (re-paired to global
// k' order) -> V d-half -> LDS exchange (1 barrier) -> PV -> out.
__global__ __launch_bounds__(256, 3) void tb_fused(
    const float* __restrict__ xg, const unsigned short* __restrict__ wbf,
    const int* __restrict__ lens, float* __restrict__ outg,
    float* __restrict__ attng) {
  // [sample 2][ntg 8][c 2][lane 64 * 8 u16] = 32 KB, lane-linear (no conflicts)
  __shared__ __align__(16) unsigned short vsh[2 * 8 * 2 * 512];

  const int tid = threadIdx.x;
  const int w = tid >> 6;
  const int lane = tid & 63;
  const int l15 = lane & 15;
  const int lq = lane >> 4;      // 0..3
  const int s = w >> 1;          // sample within block
  const int h2 = w & 1;          // q-half / d-half of this wave
  const int rt0 = h2 << 1;       // own q-tile base (global)
  const int b = blockIdx.x * 2 + s;

  const int len = lens[b];
  const float* __restrict__ xb = xg + (size_t)b * (S_LEN * DH);

  // ---- x -> afp, permuted: afp[i] = x row-tile (rt0+i)&3 (own tiles at 0,1) ----
  u16x8 afp[4][4];
#pragma unroll
  for (int i = 0; i < 4; ++i) {
    int gt = (rt0 + i) & 3;      // runtime-uniform, address only
    int row = (gt << 4) + l15;
#pragma unroll
    for (int kt = 0; kt < 4; ++kt) {
      u16x8 h = {0, 0, 0, 0, 0, 0, 0, 0};
      if (row < S_LEN) {
        const float* p = xb + row * DH + (kt << 5) + (lq << 2);
        f32x4 lo = *(const f32x4*)p;
        f32x4 hi = *(const f32x4*)(p + 16);
        h = pk8(lo, hi);
      }
      afp[i][kt] = h;
    }
  }

  // ---- E = x A x^T for own 2 q-tiles: per jp, Y-pair then fold ----
  f32x4 Ea[2][4];  // [qt][i]; lane: q=16(rt0+qt)+l15, k'-tile g(i)=(rt0+i)&3
#pragma unroll
  for (int qt = 0; qt < 2; ++qt)
#pragma unroll
    for (int i = 0; i < 4; ++i) Ea[qt][i] = f32x4{0.f, 0.f, 0.f, 0.f};

  const unsigned short* __restrict__ am = wbf + 4 * (DH * DH);  // A^T
#pragma unroll
  for (int jp = 0; jp < 4; ++jp) {
    const int t0 = jp << 1, t1 = (jp << 1) | 1;
    u16x8 wf0[4], wf1[4];
#pragma unroll
    for (int kt = 0; kt < 4; ++kt) {
      wf0[kt] = ldpi(&am[((t0 << 4) + l15) * DH + (kt << 5) + (lq << 2)]);
      wf1[kt] = ldpi(&am[((t1 << 4) + l15) * DH + (kt << 5) + (lq << 2)]);
    }
    __builtin_amdgcn_s_setprio(1);
    f32x4 ya0[2], ya1[2];
#pragma unroll
    for (int qt = 0; qt < 2; ++qt) {
      ya0[qt] = f32x4{0.f, 0.f, 0.f, 0.f};
      ya1[qt] = f32x4{0.f, 0.f, 0.f, 0.f};
    }
#pragma unroll
    for (int kt = 0; kt < 4; ++kt)
#pragma unroll
      for (int qt = 0; qt < 2; ++qt) {
        ya0[qt] = MFMA(wf0[kt], afp[qt][kt], ya0[qt]);
        ya1[qt] = MFMA(wf1[kt], afp[qt][kt], ya1[qt]);
      }
    u16x8 yp[2];
#pragma unroll
    for (int qt = 0; qt < 2; ++qt) yp[qt] = pk8(ya0[qt], ya1[qt]);
#pragma unroll
    for (int i = 0; i < 4; ++i)
#pragma unroll
      for (int qt = 0; qt < 2; ++qt)
        Ea[qt][i] = MFMA(afp[i][jp], yp[qt], Ea[qt][i]);
    __builtin_amdgcn_s_setprio(0);
  }

  // ---- scale, mask, softmax (k'-tile of slot i is g(i)=(rt0+i)&3) ----
  const float sca = 0.08838834764831845f;  // 1/sqrt(128)
  int kb[4];
#pragma unroll
  for (int i = 0; i < 4; ++i) kb[i] = (((rt0 + i) & 3) << 4) + (lq << 2);
  float inv_[2];
#pragma unroll
  for (int qt = 0; qt < 2; ++qt) {
#pragma unroll
    for (int i = 0; i < 4; ++i)
#pragma unroll
      for (int r = 0; r < 4; ++r) {
        int kk = kb[i] + r;
        Ea[qt][i][r] = (kk < len) ? Ea[qt][i][r] * sca : -1e30f;
      }
    float m = -1e30f;
#pragma unroll
    for (int i = 0; i < 4; ++i)
      m = fmaxf(m, fmaxf(fmaxf(Ea[qt][i][0], Ea[qt][i][1]),
                         fmaxf(Ea[qt][i][2], Ea[qt][i][3])));
    m = fmaxf(m, __shfl_xor(m, 16, 64));
    m = fmaxf(m, __shfl_xor(m, 32, 64));
    float sum = 0.f;
#pragma unroll
    for (int i = 0; i < 4; ++i)
#pragma unroll
      for (int r = 0; r < 4; ++r) {
        float p = __expf(Ea[qt][i][r] - m);
        Ea[qt][i][r] = p;
        sum += p;
      }
    sum += __shfl_xor(sum, 16, 64);
    sum += __shfl_xor(sum, 32, 64);
    inv_[qt] = 1.f / sum;
  }

  // ---- attn store + pp (re-paired to GLOBAL k'-tile order 0,1|2,3) ----
  const float slen = sqrtf((float)len);
  float* __restrict__ ab = attng + (size_t)b * (S_LEN * S_LEN);
  u16x8 pp[2][2];  // [c][qt]
#pragma unroll
  for (int qt = 0; qt < 2; ++qt) {
    int q = ((rt0 + qt) << 4) + l15;
    float iv = inv_[qt];
    float islen = iv * slen;
#pragma unroll
    for (int i = 0; i < 4; ++i) {
      f32x4 pv = Ea[qt][i] * iv;
      if (q < S_LEN && kb[i] < S_LEN) *(f32x4*)&ab[q * S_LEN + kb[i]] = pv;
    }
    u16x8 pA = pk8(Ea[qt][0] * islen, Ea[qt][1] * islen);  // tiles g(0),g(1)
    u16x8 pB = pk8(Ea[qt][2] * islen, Ea[qt][3] * islen);  // tiles g(2),g(3)
    pp[0][qt] = h2 ? pB : pA;  // global tiles (0,1)
    pp[1][qt] = h2 ? pA : pB;  // global tiles (2,3)
  }

  // ---- V (own d-half): ntg in [4*h2, 4*h2+4); store pi-packed to LDS ----
  {
    const unsigned short* __restrict__ wv = wbf + 2 * (DH * DH);
#pragma unroll
    for (int ntl = 0; ntl < 4; ++ntl) {
      int ntg = (h2 << 2) + ntl;
      u16x8 bfr[4];
#pragma unroll
      for (int kt = 0; kt < 4; ++kt)
        bfr[kt] = ldpi(&wv[((ntg << 4) + l15) * DH + (kt << 5) + (lq << 2)]);
      __builtin_amdgcn_s_setprio(1);
      f32x4 vacc[4];
#pragma unroll
      for (int mt = 0; mt < 4; ++mt) vacc[mt] = f32x4{0.f, 0.f, 0.f, 0.f};
#pragma unroll
      for (int kt = 0; kt < 4; ++kt)
#pragma unroll
        for (int mt = 0; mt < 4; ++mt)
          vacc[mt] = MFMA(afp[mt][kt], bfr[kt], vacc[mt]);  // rows s=16*g(mt)+..
      __builtin_amdgcn_s_setprio(0);
      u16x8 p01 = cmb(pk4(vacc[0]), pk4(vacc[1]));  // s-tiles g(0),g(1)
      u16x8 p23 = cmb(pk4(vacc[2]), pk4(vacc[3]));  // s-tiles g(2),g(3)
      u16x8 av0 = h2 ? p23 : p01;                   // global s-tiles (0,1)
      u16x8 av1 = h2 ? p01 : p23;                   // global s-tiles (2,3)
      *(u16x8*)&vsh[(((s << 3) + ntg) * 2 + 0) * 512 + (lane << 3)] = av0;
      *(u16x8*)&vsh[(((s << 3) + ntg) * 2 + 1) * 512 + (lane << 3)] = av1;
    }
  }
  __syncthreads();  // V halves exchanged

  // ---- O^T = V^T P^T (A-frags streamed from LDS) ----
  u16x8 op[4][2];  // [dp][qt]
#pragma unroll
  for (int dp = 0; dp < 4; ++dp) {
    f32x4 oa[2][2];
#pragma unroll
    for (int h = 0; h < 2; ++h) {
#pragma unroll
      for (int qt = 0; qt < 2; ++qt) oa[h][qt] = f32x4{0.f, 0.f, 0.f, 0.f};
      int ntg = (dp << 1) + h;
#pragma unroll
      for (int c = 0; c < 2; ++c) {
        u16x8 a = *(const u16x8*)&vsh[(((s << 3) + ntg) * 2 + c) * 512 + (lane << 3)];
#pragma unroll
        for (int qt = 0; qt < 2; ++qt) oa[h][qt] = MFMA(a, pp[c][qt], oa[h][qt]);
      }
    }
#pragma unroll
    for (int qt = 0; qt < 2; ++qt) op[dp][qt] = pk8(oa[0][qt], oa[1][qt]);
  }

  // ---- out^T = Wo O^T for own q rows ----
  const unsigned short* __restrict__ wop = wbf + 3 * (DH * DH);
  float* __restrict__ ob = outg + (size_t)b * (S_LEN * DH);
#pragma unroll
  for (int mo = 0; mo < 8; ++mo) {
    u16x8 wa[4];
#pragma unroll
    for (int c2 = 0; c2 < 4; ++c2)
      wa[c2] = ldpi(&wop[((mo << 4) + l15) * DH + (c2 << 5) + (lq << 2)]);
    __builtin_amdgcn_s_setprio(1);
#pragma unroll
    for (int qt = 0; qt < 2; ++qt) {
      f32x4 g = {0.f, 0.f, 0.f, 0.f};
#pragma unroll
      for (int c2 = 0; c2 < 4; ++c2) g = MFMA(wa[c2], op[c2][qt], g);
      int q = ((rt0 + qt) << 4) + l15;
      if (q < S_LEN) *(f32x4*)&ob[q * DH + (mo << 4) + (lq << 2)] = g;
    }
    __builtin_amdgcn_s_setprio(0);
  }
}

extern "C" void kernel_launch(void* const* d_in, const int* in_sizes, int n_in,
                              void* d_out, int out_size, void* d_ws, size_t ws_size,
                              hipStream_t stream) {
  const float* x  = (const float*)d_in[0];
  const float* wq = (const float*)d_in[1];
  const float* wk = (const float*)d_in[2];
  const float* wv = (const float*)d_in[3];
  const float* wo = (const float*)d_in[4];
  // d_in[5] = mask (redundant with len_sequence; unused)
  const int* lens = (const int*)d_in[6];
  const int B = in_sizes[6];  // 4096

  float* out = (float*)d_out;
  float* attn = out + (size_t)B * S_LEN * DH;
  unsigned short* wbf = (unsigned short*)d_ws;  // 5 x 128 x 128 bf16 = 160 KB

  conv_w<<<256, 256, 0, stream>>>(wq, wk, wv, wo, wbf);
  conv_a<<<64, 256, 0, stream>>>(wq, wk, wbf);
  tb_fused<<<B / 2, 256, 0, stream>>>(x, wbf, lens, out, attn);
}

// Round 11
// 84.325 us; speedup vs baseline: 2.3876x; 2.3876x over previous
//
#include <hip/hip_runtime.h>
#include <math.h>

#define S_LEN 56
#define DH 128

typedef float f32x4 __attribute__((ext_vector_type(4)));
typedef unsigned short u16x8 __attribute__((ext_vector_type(8)));
typedef unsigned short u16x4 __attribute__((ext_vector_type(4)));

__device__ __forceinline__ unsigned short f2bf(float f) {
  unsigned int u = __builtin_bit_cast(unsigned int, f);
  u += 0x7fffu + ((u >> 16) & 1u);  // RNE
  return (unsigned short)(u >> 16);
}
__device__ __forceinline__ unsigned short tobf(float f) {
  __bf16 h = (__bf16)f;
  return __builtin_bit_cast(unsigned short, h);
}
__device__ __forceinline__ u16x4 pk4(f32x4 v) {
  u16x4 r;
  r[0] = tobf(v[0]); r[1] = tobf(v[1]); r[2] = tobf(v[2]); r[3] = tobf(v[3]);
  return r;
}
__device__ __forceinline__ u16x8 pk8(f32x4 a, f32x4 b) {
  u16x8 r;
  r[0] = tobf(a[0]); r[1] = tobf(a[1]); r[2] = tobf(a[2]); r[3] = tobf(a[3]);
  r[4] = tobf(b[0]); r[5] = tobf(b[1]); r[6] = tobf(b[2]); r[7] = tobf(b[3]);
  return r;
}
__device__ __forceinline__ u16x8 cmb(u16x4 lo, u16x4 hi) {
  u16x8 r;
  r[0] = lo[0]; r[1] = lo[1]; r[2] = lo[2]; r[3] = lo[3];
  r[4] = hi[0]; r[5] = hi[1]; r[6] = hi[2]; r[7] = hi[3];
  return r;
}

template <typename V>
__device__ __forceinline__ auto mfma_sel(V a, V b, f32x4 c, int)
    -> decltype(__builtin_amdgcn_mfma_f32_16x16x32_bf16(a, b, c, 0, 0, 0)) {
  return __builtin_amdgcn_mfma_f32_16x16x32_bf16(a, b, c, 0, 0, 0);
}
template <typename V, typename E = __bf16>
__device__ __forceinline__ f32x4 mfma_sel(V a, V b, f32x4 c, long) {
  typedef E bfv __attribute__((ext_vector_type(8)));
  return __builtin_amdgcn_mfma_f32_16x16x32_bf16(
      __builtin_bit_cast(bfv, a), __builtin_bit_cast(bfv, b), c, 0, 0, 0);
}
__device__ __forceinline__ f32x4 MFMA(u16x8 a, u16x8 b, f32x4 c) {
  return mfma_sel(a, b, c, 0);
}

__global__ void conv_w(const float* __restrict__ wq, const float* __restrict__ wk,
                       const float* __restrict__ wv, const float* __restrict__ wo,
                       unsigned short* __restrict__ o) {
  int i = blockIdx.x * 256 + threadIdx.x;  // 0..65535
  int m = i >> 14, r = i & 16383;
  const float* src = (m == 0) ? wq : (m == 1) ? wk : (m == 2) ? wv : wo;
  o[i] = f2bf(src[r]);
}

// A^T where A = Wq^T Wk (E = x A x^T); r9-proven orientation.
__global__ void conv_a(const float* __restrict__ wq, const float* __restrict__ wk,
                       unsigned short* __restrict__ o) {
  int i = blockIdx.x * 256 + threadIdx.x;  // 0..16383
  int r = i >> 7, c = i & 127;
  float s = 0.f;
#pragma unroll 8
  for (int d = 0; d < DH; ++d) s += wq[d * DH + r] * wk[d * DH + c];
  o[4 * 16384 + c * DH + r] = f2bf(s);  // A^T[c][r] = A[r][c]
}

// Cooperative 128x128-u16 weight stage: coalesced 16B loads, swizzled
// ds_write_b128 (granule ^= row&7 kills the 256B-stride bank conflict).
__device__ __forceinline__ void stageW(const unsigned short* __restrict__ src,
                                       unsigned short* wsh, int tid) {
#pragma unroll
  for (int half = 0; half < 2; ++half) {
    u16x8 v[8];
#pragma unroll
    for (int j = 0; j < 8; ++j)
      v[j] = *(const u16x8*)(src + (((half * 8 + j) * 256 + tid) << 3));
#pragma unroll
    for (int j = 0; j < 8; ++j) {
      int row = (half * 8 + j) * 16 + (tid >> 4);
      int g = (tid & 15) ^ (row & 7);
      *(u16x8*)((char*)wsh + (row << 8) + (g << 4)) = v[j];
    }
  }
}

// pi-fragment read from the swizzled LDS weight tile (ldpi equivalent):
// 4 u16 at col kt*32+lq*4 and 4 at +16 of row `row`.
__device__ __forceinline__ u16x8 ldw(const unsigned short* wsh, int row,
                                     int kt, int lq) {
  int m = (row & 7) << 4;
  int p = (kt << 3) + lq;                     // 8-byte piece index
  int a0 = (row << 8) + (((p) << 3) ^ m);
  int a1 = (row << 8) + (((p + 4) << 3) ^ m);
  u16x4 lo = *(const u16x4*)((const char*)wsh + a0);
  u16x4 hi = *(const u16x4*)((const char*)wsh + a1);
  return cmb(lo, hi);
}

// One WAVE per sample (r9 pipeline). NEW: weights are staged into one 32 KB
// LDS buffer per BLOCK (A^T -> Wv -> Wo, 5 barriers) instead of each wave
// gather-loading 96 KB of weights from L2 — the r7/r9/r10 latency binder.
__global__ __launch_bounds__(256, 2) void tb_fused(
    const float* __restrict__ xg, const unsigned short* __restrict__ wbf,
    const int* __restrict__ lens, float* __restrict__ outg,
    float* __restrict__ attng) {
  __shared__ __align__(16) unsigned short wsh[DH * DH];  // 32 KB staging

  const int tid = threadIdx.x;
  const int w = tid >> 6;        // wave id -> sample
  const int lane = tid & 63;
  const int l15 = lane & 15;
  const int lq = lane >> 4;      // 0..3
  const int b = blockIdx.x * 4 + w;

  const int len = lens[b];
  const float* __restrict__ xb = xg + (size_t)b * (S_LEN * DH);

  // ---- stage A^T ----
  stageW(wbf + 4 * (DH * DH), wsh, tid);

  // ---- x -> registers afp[rt][kt], pi map ----
  u16x8 afp[4][4];
#pragma unroll
  for (int rt = 0; rt < 4; ++rt) {
    int row = (rt << 4) + l15;
#pragma unroll
    for (int kt = 0; kt < 4; ++kt) {
      u16x8 h = {0, 0, 0, 0, 0, 0, 0, 0};
      if (row < S_LEN) {
        const float* p = xb + row * DH + (kt << 5) + (lq << 2);
        f32x4 lo = *(const f32x4*)p;
        f32x4 hi = *(const f32x4*)(p + 16);
        h = pk8(lo, hi);
      }
      afp[rt][kt] = h;
    }
  }
  __syncthreads();  // A^T staged

  // ---- E = x A x^T: per jp, Y-pair (d'-chunk) then fold into Ea ----
  f32x4 Ea[4][4];  // [qt][nt]; lane: q=16qt+l15, k'=16nt+4lq+r (r9-proven)
#pragma unroll
  for (int qt = 0; qt < 4; ++qt)
#pragma unroll
    for (int nt = 0; nt < 4; ++nt) Ea[qt][nt] = f32x4{0.f, 0.f, 0.f, 0.f};

#pragma unroll
  for (int jp = 0; jp < 4; ++jp) {
    const int t0 = jp << 1, t1 = (jp << 1) | 1;
    u16x8 wf0[4], wf1[4];
#pragma unroll
    for (int kt = 0; kt < 4; ++kt) {
      wf0[kt] = ldw(wsh, (t0 << 4) + l15, kt, lq);
      wf1[kt] = ldw(wsh, (t1 << 4) + l15, kt, lq);
    }
    __builtin_amdgcn_s_setprio(1);
    f32x4 ya0[4], ya1[4];
#pragma unroll
    for (int qt = 0; qt < 4; ++qt) {
      ya0[qt] = f32x4{0.f, 0.f, 0.f, 0.f};
      ya1[qt] = f32x4{0.f, 0.f, 0.f, 0.f};
    }
#pragma unroll
    for (int kt = 0; kt < 4; ++kt)
#pragma unroll
      for (int qt = 0; qt < 4; ++qt) {
        ya0[qt] = MFMA(wf0[kt], afp[qt][kt], ya0[qt]);
        ya1[qt] = MFMA(wf1[kt], afp[qt][kt], ya1[qt]);
      }
    u16x8 yp[4];
#pragma unroll
    for (int qt = 0; qt < 4; ++qt) yp[qt] = pk8(ya0[qt], ya1[qt]);
#pragma unroll
    for (int nt = 0; nt < 4; ++nt)
#pragma unroll
      for (int qt = 0; qt < 4; ++qt)
        Ea[qt][nt] = MFMA(afp[nt][jp], yp[qt], Ea[qt][nt]);
    __builtin_amdgcn_s_setprio(0);
  }

  // ---- scale, mask, softmax per q-tile ----
  const float sca = 0.08838834764831845f;  // 1/sqrt(128)
  float inv_[4];
#pragma unroll
  for (int qt = 0; qt < 4; ++qt) {
#pragma unroll
    for (int nt = 0; nt < 4; ++nt)
#pragma unroll
      for (int r = 0; r < 4; ++r) {
        int kk = (nt << 4) + (lq << 2) + r;
        Ea[qt][nt][r] = (kk < len) ? Ea[qt][nt][r] * sca : -1e30f;
      }
    float m = -1e30f;
#pragma unroll
    for (int nt = 0; nt < 4; ++nt)
      m = fmaxf(m, fmaxf(fmaxf(Ea[qt][nt][0], Ea[qt][nt][1]),
                         fmaxf(Ea[qt][nt][2], Ea[qt][nt][3])));
    m = fmaxf(m, __shfl_xor(m, 16, 64));
    m = fmaxf(m, __shfl_xor(m, 32, 64));
    float s = 0.f;
#pragma unroll
    for (int nt = 0; nt < 4; ++nt)
#pragma unroll
      for (int r = 0; r < 4; ++r) {
        float p = __expf(Ea[qt][nt][r] - m);
        Ea[qt][nt][r] = p;
        s += p;
      }
    s += __shfl_xor(s, 16, 64);
    s += __shfl_xor(s, 32, 64);
    inv_[qt] = 1.f / s;
  }

  // ---- attn store (f32x4) + P^T pack pp[c][qt]; Ea dies here ----
  const float slen = sqrtf((float)len);
  float* __restrict__ ab = attng + (size_t)b * (S_LEN * S_LEN);
  u16x8 pp[2][4];
#pragma unroll
  for (int qt = 0; qt < 4; ++qt) {
    int q = (qt << 4) + l15;
    float iv = inv_[qt];
    float islen = iv * slen;
#pragma unroll
    for (int nt = 0; nt < 4; ++nt) {
      int cs = (nt << 4) + (lq << 2);
      f32x4 pv = Ea[qt][nt] * iv;
      if (q < S_LEN && cs < S_LEN) *(f32x4*)&ab[q * S_LEN + cs] = pv;
    }
    pp[0][qt] = pk8(Ea[qt][0] * islen, Ea[qt][1] * islen);
    pp[1][qt] = pk8(Ea[qt][2] * islen, Ea[qt][3] * islen);
  }

  __syncthreads();  // all E-phase LDS reads done
  stageW(wbf + 2 * (DH * DH), wsh, tid);  // stage Wv
  __syncthreads();

  // ---- V = x @ Wv^T in registers; av pair-packed (pi map, r9-proven) ----
  u16x8 av[8][2];
#pragma unroll
  for (int nt = 0; nt < 8; ++nt) {
    u16x8 bfr[4];
#pragma unroll
    for (int kt = 0; kt < 4; ++kt)
      bfr[kt] = ldw(wsh, (nt << 4) + l15, kt, lq);
    __builtin_amdgcn_s_setprio(1);
    f32x4 vacc[4];
#pragma unroll
    for (int mt = 0; mt < 4; ++mt) vacc[mt] = f32x4{0.f, 0.f, 0.f, 0.f};
#pragma unroll
    for (int kt = 0; kt < 4; ++kt)
#pragma unroll
      for (int mt = 0; mt < 4; ++mt)
        vacc[mt] = MFMA(afp[mt][kt], bfr[kt], vacc[mt]);
    av[nt][0] = cmb(pk4(vacc[0]), pk4(vacc[1]));
    av[nt][1] = cmb(pk4(vacc[2]), pk4(vacc[3]));
    __builtin_amdgcn_s_setprio(0);
  }

  __syncthreads();  // all V-phase LDS reads done
  stageW(wbf + 3 * (DH * DH), wsh, tid);  // stage Wo
  __syncthreads();

  // ---- O^T = V^T P^T entirely in registers ----
  u16x8 op[4][4];  // [dp][qt]
  __builtin_amdgcn_s_setprio(1);
#pragma unroll
  for (int dp = 0; dp < 4; ++dp) {
    f32x4 oa[2][4];
#pragma unroll
    for (int h = 0; h < 2; ++h) {
#pragma unroll
      for (int qt = 0; qt < 4; ++qt) oa[h][qt] = f32x4{0.f, 0.f, 0.f, 0.f};
#pragma unroll
      for (int c = 0; c < 2; ++c) {
#pragma unroll
        for (int qt = 0; qt < 4; ++qt)
          oa[h][qt] = MFMA(av[(dp << 1) | h][c], pp[c][qt], oa[h][qt]);
      }
    }
#pragma unroll
    for (int qt = 0; qt < 4; ++qt) op[dp][qt] = pk8(oa[0][qt], oa[1][qt]);
  }
  __builtin_amdgcn_s_setprio(0);

  // ---- out^T = Wo O^T : A-frags from staged LDS ----
  float* __restrict__ ob = outg + (size_t)b * (S_LEN * DH);
#pragma unroll
  for (int mo = 0; mo < 8; ++mo) {
    u16x8 wa[4];
#pragma unroll
    for (int c2 = 0; c2 < 4; ++c2)
      wa[c2] = ldw(wsh, (mo << 4) + l15, c2, lq);
    __builtin_amdgcn_s_setprio(1);
#pragma unroll
    for (int qt = 0; qt < 4; ++qt) {
      f32x4 g = {0.f, 0.f, 0.f, 0.f};
#pragma unroll
      for (int c2 = 0; c2 < 4; ++c2) g = MFMA(wa[c2], op[c2][qt], g);
      int q = (qt << 4) + l15;
      if (q < S_LEN) *(f32x4*)&ob[q * DH + (mo << 4) + (lq << 2)] = g;
    }
    __builtin_amdgcn_s_setprio(0);
  }
}

extern "C" void kernel_launch(void* const* d_in, const int* in_sizes, int n_in,
                              void* d_out, int out_size, void* d_ws, size_t ws_size,
                              hipStream_t stream) {
  const float* x  = (const float*)d_in[0];
  const float* wq = (const float*)d_in[1];
  const float* wk = (const float*)d_in[2];
  const float* wv = (const float*)d_in[3];
  const float* wo = (const float*)d_in[4];
  // d_in[5] = mask (redundant with len_sequence; unused)
  const int* lens = (const int*)d_in[6];
  const int B = in_sizes[6];  // 4096

  float* out = (float*)d_out;
  float* attn = out + (size_t)B * S_LEN * DH;
  unsigned short* wbf = (unsigned short*)d_ws;  // 5 x 128 x 128 bf16 = 160 KB

  conv_w<<<256, 256, 0, stream>>>(wq, wk, wv, wo, wbf);
  conv_a<<<64, 256, 0, stream>>>(wq, wk, wbf);
  tb_fused<<<B / 4, 256, 0, stream>>>(x, wbf, lens, out, attn);
}

// Round 13
// 80.644 us; speedup vs baseline: 2.4966x; 1.0457x over previous
//
#include <hip/hip_runtime.h>
#include <math.h>

#define S_LEN 56
#define DH 128

typedef float f32x4 __attribute__((ext_vector_type(4)));
typedef unsigned short u16x8 __attribute__((ext_vector_type(8)));
typedef unsigned short u16x4 __attribute__((ext_vector_type(4)));

__device__ __forceinline__ unsigned short f2bf(float f) {
  unsigned int u = __builtin_bit_cast(unsigned int, f);
  u += 0x7fffu + ((u >> 16) & 1u);  // RNE
  return (unsigned short)(u >> 16);
}
__device__ __forceinline__ unsigned short tobf(float f) {
  __bf16 h = (__bf16)f;
  return __builtin_bit_cast(unsigned short, h);
}
__device__ __forceinline__ u16x4 pk4(f32x4 v) {
  u16x4 r;
  r[0] = tobf(v[0]); r[1] = tobf(v[1]); r[2] = tobf(v[2]); r[3] = tobf(v[3]);
  return r;
}
__device__ __forceinline__ u16x8 pk8(f32x4 a, f32x4 b) {
  u16x8 r;
  r[0] = tobf(a[0]); r[1] = tobf(a[1]); r[2] = tobf(a[2]); r[3] = tobf(a[3]);
  r[4] = tobf(b[0]); r[5] = tobf(b[1]); r[6] = tobf(b[2]); r[7] = tobf(b[3]);
  return r;
}
__device__ __forceinline__ u16x8 cmb(u16x4 lo, u16x4 hi) {
  u16x8 r;
  r[0] = lo[0]; r[1] = lo[1]; r[2] = lo[2]; r[3] = lo[3];
  r[4] = hi[0]; r[5] = hi[1]; r[6] = hi[2]; r[7] = hi[3];
  return r;
}

template <typename V>
__device__ __forceinline__ auto mfma_sel(V a, V b, f32x4 c, int)
    -> decltype(__builtin_amdgcn_mfma_f32_16x16x32_bf16(a, b, c, 0, 0, 0)) {
  return __builtin_amdgcn_mfma_f32_16x16x32_bf16(a, b, c, 0, 0, 0);
}
template <typename V, typename E = __bf16>
__device__ __forceinline__ f32x4 mfma_sel(V a, V b, f32x4 c, long) {
  typedef E bfv __attribute__((ext_vector_type(8)));
  return __builtin_amdgcn_mfma_f32_16x16x32_bf16(
      __builtin_bit_cast(bfv, a), __builtin_bit_cast(bfv, b), c, 0, 0, 0);
}
__device__ __forceinline__ f32x4 MFMA(u16x8 a, u16x8 b, f32x4 c) {
  return mfma_sel(a, b, c, 0);
}

__global__ void conv_w(const float* __restrict__ wq, const float* __restrict__ wk,
                       const float* __restrict__ wv, const float* __restrict__ wo,
                       unsigned short* __restrict__ o) {
  int i = blockIdx.x * 256 + threadIdx.x;  // 0..65535
  int m = i >> 14, r = i & 16383;
  const float* src = (m == 0) ? wq : (m == 1) ? wk : (m == 2) ? wv : wo;
  o[i] = f2bf(src[r]);
}

// A^T where A = Wq^T Wk (E = x A x^T); r9-proven orientation.
__global__ void conv_a(const float* __restrict__ wq, const float* __restrict__ wk,
                       unsigned short* __restrict__ o) {
  int i = blockIdx.x * 256 + threadIdx.x;  // 0..16383
  int r = i >> 7, c = i & 127;
  float s = 0.f;
#pragma unroll 8
  for (int d = 0; d < DH; ++d) s += wq[d * DH + r] * wk[d * DH + c];
  o[4 * 16384 + c * DH + r] = f2bf(s);  // A^T[c][r] = A[r][c]
}

// Cooperative 128x128-u16 weight stage. FIXED vs r11/r12: exactly 8 chunks
// (rows 0..127, 32 KB) — r11's version staged 16 chunks (256 rows); the
// second 8 were OOB-dropped at 32 KB allocation but CORRUPTED buf1 at 64 KB
// (the r12 failure: cross-wave race with V-phase buf1 reads).
__device__ __forceinline__ void stageW(const unsigned short* __restrict__ src,
                                       unsigned short* wsh, int tid) {
  u16x8 v[8];
#pragma unroll
  for (int j = 0; j < 8; ++j)
    v[j] = *(const u16x8*)(src + ((j * 256 + tid) << 3));
#pragma unroll
  for (int j = 0; j < 8; ++j) {
    int row = j * 16 + (tid >> 4);
    int g = (tid & 15) ^ (row & 7);
    *(u16x8*)((char*)wsh + (row << 8) + (g << 4)) = v[j];
  }
}

// pi-fragment read from the swizzled LDS weight tile (r11-proven).
__device__ __forceinline__ u16x8 ldw(const unsigned short* wsh, int row,
                                     int kt, int lq) {
  int m = (row & 7) << 4;
  int p = (kt << 3) + lq;                     // 8-byte piece index
  int a0 = (row << 8) + (((p) << 3) ^ m);
  int a1 = (row << 8) + (((p + 4) << 3) ^ m);
  u16x4 lo = *(const u16x4*)((const char*)wsh + a0);
  u16x4 hi = *(const u16x4*)((const char*)wsh + a1);
  return cmb(lo, hi);
}

// r11 pipeline + double-buffered staging: A^T->buf0 and Wv->buf1 staged
// upfront together (1 barrier), Wo staged split (8 loads issued before the
// V-phase MFMAs, written to buf0 after — T14). Writes only touch buf0,
// which no wave reads between B2 and B3 -> race-free. 3 barriers total.
__global__ __launch_bounds__(256, 2) void tb_fused(
    const float* __restrict__ xg, const unsigned short* __restrict__ wbf,
    const int* __restrict__ lens, float* __restrict__ outg,
    float* __restrict__ attng) {
  __shared__ __align__(16) unsigned short wsh[2 * DH * DH];  // 64 KB, 2 bufs
  unsigned short* buf0 = wsh;             // A^T, later Wo
  unsigned short* buf1 = wsh + DH * DH;   // Wv

  const int tid = threadIdx.x;
  const int w = tid >> 6;        // wave id -> sample
  const int lane = tid & 63;
  const int l15 = lane & 15;
  const int lq = lane >> 4;      // 0..3
  const int b = blockIdx.x * 4 + w;

  const int len = lens[b];
  const float* __restrict__ xb = xg + (size_t)b * (S_LEN * DH);

  // ---- stage A^T -> buf0, Wv -> buf1 (16 loads in flight) ----
  stageW(wbf + 4 * (DH * DH), buf0, tid);
  stageW(wbf + 2 * (DH * DH), buf1, tid);

  // ---- x -> registers afp[rt][kt], pi map (overlaps staging latency) ----
  u16x8 afp[4][4];
#pragma unroll
  for (int rt = 0; rt < 4; ++rt) {
    int row = (rt << 4) + l15;
#pragma unroll
    for (int kt = 0; kt < 4; ++kt) {
      u16x8 h = {0, 0, 0, 0, 0, 0, 0, 0};
      if (row < S_LEN) {
        const float* p = xb + row * DH + (kt << 5) + (lq << 2);
        f32x4 lo = *(const f32x4*)p;
        f32x4 hi = *(const f32x4*)(p + 16);
        h = pk8(lo, hi);
      }
      afp[rt][kt] = h;
    }
  }
  __syncthreads();  // B1: A^T + Wv staged

  // ---- E = x A x^T: per jp, Y-pair (d'-chunk) then fold into Ea ----
  f32x4 Ea[4][4];  // [qt][nt]; lane: q=16qt+l15, k'=16nt+4lq+r (r9-proven)
#pragma unroll
  for (int qt = 0; qt < 4; ++qt)
#pragma unroll
    for (int nt = 0; nt < 4; ++nt) Ea[qt][nt] = f32x4{0.f, 0.f, 0.f, 0.f};

#pragma unroll
  for (int jp = 0; jp < 4; ++jp) {
    const int t0 = jp << 1, t1 = (jp << 1) | 1;
    u16x8 wf0[4], wf1[4];
#pragma unroll
    for (int kt = 0; kt < 4; ++kt) {
      wf0[kt] = ldw(buf0, (t0 << 4) + l15, kt, lq);
      wf1[kt] = ldw(buf0, (t1 << 4) + l15, kt, lq);
    }
    __builtin_amdgcn_s_setprio(1);
    f32x4 ya0[4], ya1[4];
#pragma unroll
    for (int qt = 0; qt < 4; ++qt) {
      ya0[qt] = f32x4{0.f, 0.f, 0.f, 0.f};
      ya1[qt] = f32x4{0.f, 0.f, 0.f, 0.f};
    }
#pragma unroll
    for (int kt = 0; kt < 4; ++kt)
#pragma unroll
      for (int qt = 0; qt < 4; ++qt) {
        ya0[qt] = MFMA(wf0[kt], afp[qt][kt], ya0[qt]);
        ya1[qt] = MFMA(wf1[kt], afp[qt][kt], ya1[qt]);
      }
    u16x8 yp[4];
#pragma unroll
    for (int qt = 0; qt < 4; ++qt) yp[qt] = pk8(ya0[qt], ya1[qt]);
#pragma unroll
    for (int nt = 0; nt < 4; ++nt)
#pragma unroll
      for (int qt = 0; qt < 4; ++qt)
        Ea[qt][nt] = MFMA(afp[nt][jp], yp[qt], Ea[qt][nt]);
    __builtin_amdgcn_s_setprio(0);
  }

  // ---- scale, mask, softmax per q-tile ----
  const float sca = 0.08838834764831845f;  // 1/sqrt(128)
  float inv_[4];
#pragma unroll
  for (int qt = 0; qt < 4; ++qt) {
#pragma unroll
    for (int nt = 0; nt < 4; ++nt)
#pragma unroll
      for (int r = 0; r < 4; ++r) {
        int kk = (nt << 4) + (lq << 2) + r;
        Ea[qt][nt][r] = (kk < len) ? Ea[qt][nt][r] * sca : -1e30f;
      }
    float m = -1e30f;
#pragma unroll
    for (int nt = 0; nt < 4; ++nt)
      m = fmaxf(m, fmaxf(fmaxf(Ea[qt][nt][0], Ea[qt][nt][1]),
                         fmaxf(Ea[qt][nt][2], Ea[qt][nt][3])));
    m = fmaxf(m, __shfl_xor(m, 16, 64));
    m = fmaxf(m, __shfl_xor(m, 32, 64));
    float s = 0.f;
#pragma unroll
    for (int nt = 0; nt < 4; ++nt)
#pragma unroll
      for (int r = 0; r < 4; ++r) {
        float p = __expf(Ea[qt][nt][r] - m);
        Ea[qt][nt][r] = p;
        s += p;
      }
    s += __shfl_xor(s, 16, 64);
    s += __shfl_xor(s, 32, 64);
    inv_[qt] = 1.f / s;
  }

  // ---- attn store (f32x4) + P^T pack pp[c][qt]; Ea dies here ----
  const float slen = sqrtf((float)len);
  float* __restrict__ ab = attng + (size_t)b * (S_LEN * S_LEN);
  u16x8 pp[2][4];
#pragma unroll
  for (int qt = 0; qt < 4; ++qt) {
    int q = (qt << 4) + l15;
    float iv = inv_[qt];
    float islen = iv * slen;
#pragma unroll
    for (int nt = 0; nt < 4; ++nt) {
      int cs = (nt << 4) + (lq << 2);
      f32x4 pv = Ea[qt][nt] * iv;
      if (q < S_LEN && cs < S_LEN) *(f32x4*)&ab[q * S_LEN + cs] = pv;
    }
    pp[0][qt] = pk8(Ea[qt][0] * islen, Ea[qt][1] * islen);
    pp[1][qt] = pk8(Ea[qt][2] * islen, Ea[qt][3] * islen);
  }

  __syncthreads();  // B2: all buf0 (A^T) reads done; Wo may overwrite it

  // ---- V = x @ Wv^T (buf1) with Wo staging split (T14): 8 loads issued,
  //      V nt 0..7 MFMAs hide the latency, then write to buf0 (disjoint
  //      from buf1 -> no cross-wave hazard), then B3.
  u16x8 av[8][2];
  const unsigned short* __restrict__ wos = wbf + 3 * (DH * DH);
  {
    u16x8 st[8];
#pragma unroll
    for (int j = 0; j < 8; ++j)
      st[j] = *(const u16x8*)(wos + ((j * 256 + tid) << 3));
#pragma unroll
    for (int nt = 0; nt < 8; ++nt) {
      u16x8 bfr[4];
#pragma unroll
      for (int kt = 0; kt < 4; ++kt)
        bfr[kt] = ldw(buf1, (nt << 4) + l15, kt, lq);
      __builtin_amdgcn_s_setprio(1);
      f32x4 vacc[4];
#pragma unroll
      for (int mt = 0; mt < 4; ++mt) vacc[mt] = f32x4{0.f, 0.f, 0.f, 0.f};
#pragma unroll
      for (int kt = 0; kt < 4; ++kt)
#pragma unroll
        for (int mt = 0; mt < 4; ++mt)
          vacc[mt] = MFMA(afp[mt][kt], bfr[kt], vacc[mt]);
      av[nt][0] = cmb(pk4(vacc[0]), pk4(vacc[1]));
      av[nt][1] = cmb(pk4(vacc[2]), pk4(vacc[3]));
      __builtin_amdgcn_s_setprio(0);
    }
#pragma unroll
    for (int j = 0; j < 8; ++j) {
      int row = j * 16 + (tid >> 4);
      int g = (tid & 15) ^ (row & 7);
      *(u16x8*)((char*)buf0 + (row << 8) + (g << 4)) = st[j];
    }
  }
  __syncthreads();  // B3: Wo staged

  // ---- O^T = V^T P^T entirely in registers ----
  u16x8 op[4][4];  // [dp][qt]
  __builtin_amdgcn_s_setprio(1);
#pragma unroll
  for (int dp = 0; dp < 4; ++dp) {
    f32x4 oa[2][4];
#pragma unroll
    for (int h = 0; h < 2; ++h) {
#pragma unroll
      for (int qt = 0; qt < 4; ++qt) oa[h][qt] = f32x4{0.f, 0.f, 0.f, 0.f};
#pragma unroll
      for (int c = 0; c < 2; ++c) {
#pragma unroll
        for (int qt = 0; qt < 4; ++qt)
          oa[h][qt] = MFMA(av[(dp << 1) | h][c], pp[c][qt], oa[h][qt]);
      }
    }
#pragma unroll
    for (int qt = 0; qt < 4; ++qt) op[dp][qt] = pk8(oa[0][qt], oa[1][qt]);
  }
  __builtin_amdgcn_s_setprio(0);

  // ---- out^T = Wo O^T : A-frags from staged LDS (buf0) ----
  float* __restrict__ ob = outg + (size_t)b * (S_LEN * DH);
#pragma unroll
  for (int mo = 0; mo < 8; ++mo) {
    u16x8 wa[4];
#pragma unroll
    for (int c2 = 0; c2 < 4; ++c2)
      wa[c2] = ldw(buf0, (mo << 4) + l15, c2, lq);
    __builtin_amdgcn_s_setprio(1);
#pragma unroll
    for (int qt = 0; qt < 4; ++qt) {
      f32x4 g = {0.f, 0.f, 0.f, 0.f};
#pragma unroll
      for (int c2 = 0; c2 < 4; ++c2) g = MFMA(wa[c2], op[c2][qt], g);
      int q = (qt << 4) + l15;
      if (q < S_LEN) *(f32x4*)&ob[q * DH + (mo << 4) + (lq << 2)] = g;
    }
    __builtin_amdgcn_s_setprio(0);
  }
}

extern "C" void kernel_launch(void* const* d_in, const int* in_sizes, int n_in,
                              void* d_out, int out_size, void* d_ws, size_t ws_size,
                              hipStream_t stream) {
  const float* x  = (const float*)d_in[0];
  const float* wq = (const float*)d_in[1];
  const float* wk = (const float*)d_in[2];
  const float* wv = (const float*)d_in[3];
  const float* wo = (const float*)d_in[4];
  // d_in[5] = mask (redundant with len_sequence; unused)
  const int* lens = (const int*)d_in[6];
  const int B = in_sizes[6];  // 4096

  float* out = (float*)d_out;
  float* attn = out + (size_t)B * S_LEN * DH;
  unsigned short* wbf = (unsigned short*)d_ws;  // 5 x 128 x 128 bf16 = 160 KB

  conv_w<<<256, 256, 0, stream>>>(wq, wk, wv, wo, wbf);
  conv_a<<<64, 256, 0, stream>>>(wq, wk, wbf);
  tb_fused<<<B / 4, 256, 0, stream>>>(x, wbf, lens, out, attn);
}